// Round 6
// baseline (670.266 us; speedup 1.0000x reference)
//
#include <hip/hip_runtime.h>
#include <hip/hip_bf16.h>

typedef __attribute__((ext_vector_type(4))) float f32x4;
typedef __attribute__((ext_vector_type(8))) short bf16x8;
typedef __attribute__((ext_vector_type(4))) unsigned short u16x4;
typedef unsigned short u16;

constexpr int HH = 384, WW = 384;
constexpr int AWP = 386;               // padded activation width (+1 halo each side)
constexpr int ASTR = AWP * 64;         // elements per padded activation row
constexpr int NPIX = HH * WW;          // 147456
constexpr int NPIX3 = NPIX * 3;        // 442368 (one output tensor)
constexpr int DP = 398, DPLANE = DP * DP;  // data padded by 7 each side
constexpr size_t ACT_BYTES = (size_t)AWP * AWP * 64 * 2;  // 19,071,488
constexpr int WSW = 72 * 512;          // swizzled weights per conv: 72 iters * 64 lanes * 8

__device__ __forceinline__ u16 f2bf(float f) {
  union { __hip_bfloat16 h; u16 u; } v; v.h = __float2bfloat16(f); return v.u;
}
__device__ __forceinline__ float bf2f(u16 u) {
  union { float f; unsigned int i; } v; v.i = ((unsigned int)u) << 16; return v.f;
}

// ---------------- weight/bias repack ----------------
// wpack[c][iter][lane][j] bf16 pre-swizzled to MFMA A-fragment order:
//   iter = (tap*2 + ich)*4 + m;  oc = m*16 + (lane&15);  ic = ich*32 + (lane>>4)*8 + j
// bpack[c][oc] f32 (oc>=35 zeroed for conv 6); wfr[ictap][oc] f32 for first conv
__global__ void repack_kern(const float* __restrict__ w1, const float* __restrict__ w2,
                            const float* __restrict__ wo, const float* __restrict__ b1,
                            const float* __restrict__ b2, const float* __restrict__ bo,
                            const float* __restrict__ wf,
                            u16* __restrict__ wpack, float* __restrict__ bpack,
                            float* __restrict__ wfr)
{
  const int idx = blockIdx.x * 256 + threadIdx.x;
  constexpr int NW = 7 * WSW;
  if (idx < NW) {
    const int c = idx / WSW;
    const int r = idx % WSW;
    const int iter = r / 512;
    const int lane = (r % 512) / 8;
    const int j = r % 8;
    const int tap = iter >> 3;
    const int ich = (iter >> 2) & 1;
    const int m = iter & 3;
    const int oc = m * 16 + (lane & 15);
    const int ic = ich * 32 + (lane >> 4) * 8 + j;
    float v;
    if (c < 6) {
      const float* s = (c & 1) ? w2 : w1;
      v = s[(((c >> 1) * 64 + oc) * 64 + ic) * 9 + tap];
    } else {
      v = (oc < 35) ? wo[(oc * 64 + ic) * 9 + tap] : 0.f;
    }
    wpack[idx] = f2bf(v);
  } else if (idx < NW + 448) {
    const int t = idx - NW;
    const int c = t / 64, oc = t % 64;
    float v;
    if (c < 6) v = ((c & 1) ? b2 : b1)[(c >> 1) * 64 + oc];
    else v = (oc < 35) ? bo[oc] : 0.f;
    bpack[t] = v;
  } else if (idx < NW + 448 + 3456) {
    const int t = idx - NW - 448;
    const int ictap = t / 64, oc = t % 64;
    wfr[t] = wf[oc * 54 + ictap];
  }
}

// ---------------- pad-copy data (fp32, halo 7) ----------------
__global__ void padcopy_kern(const float* __restrict__ data, float* __restrict__ dpad)
{
  const int idx = blockIdx.x * 256 + threadIdx.x;  // exactly 442368 threads
  const int c = idx / NPIX, r = idx % NPIX;
  const int y = r / WW, x = r % WW;
  dpad[c * DPLANE + (y + 7) * DP + (x + 7)] = data[idx];
}

// ---------------- first conv: 6 -> 64, fp32 direct, writes NHWC bf16 ----------------
// block = (64 px, 4 oc-groups); each thread computes 16 oc for one pixel.
__global__ __launch_bounds__(256)
void conv1_kern(const float* __restrict__ din, const float* __restrict__ wr,
                const float* __restrict__ bias, u16* __restrict__ outb)
{
  const int px = blockIdx.x * 64 + threadIdx.x;   // 2304*64 = NPIX exactly
  const int ocg = threadIdx.y;                    // 0..3
  const int y = px / WW, x = px % WW;
  f32x4 acc[4];
  #pragma unroll
  for (int j = 0; j < 4; ++j) acc[j] = *(const f32x4*)(bias + ocg * 16 + j * 4);
  for (int ic = 0; ic < 6; ++ic) {
    #pragma unroll
    for (int kr = 0; kr < 3; ++kr) {
      const int yy = y + kr - 1;
      #pragma unroll
      for (int kc = 0; kc < 3; ++kc) {
        const int xx = x + kc - 1;
        float v = 0.f;
        if (yy >= 0 && yy < HH && xx >= 0 && xx < WW)
          v = din[ic * NPIX + yy * WW + xx];
        const float* w = wr + ((ic * 3 + kr) * 3 + kc) * 64 + ocg * 16;
        #pragma unroll
        for (int j = 0; j < 4; ++j) {
          const f32x4 wv = *(const f32x4*)(w + j * 4);
          acc[j] += wv * v;
        }
      }
    }
  }
  u16* ob = outb + ((size_t)(y + 1) * AWP + (x + 1)) * 64 + ocg * 16;
  #pragma unroll
  for (int j = 0; j < 4; ++j) {
    u16x4 s;
    #pragma unroll
    for (int t = 0; t < 4; ++t) s[t] = f2bf(acc[j][t]);
    *(u16x4*)(ob + j * 4) = s;
  }
}

// ---------------- MFMA implicit-GEMM 3x3 conv, 64->64 (or ->35 planar f32) ----------------
// MODE 0: +bias, relu, store bf16 NHWC padded
// MODE 1: +bias, +residual (in-place on outb), store bf16 NHWC padded
// MODE 2: +bias, store f32 planar [oc][pix] for oc < 35
template<int MODE>
__global__ __launch_bounds__(128)
void conv_mfma(const u16* __restrict__ in, const u16* __restrict__ wp,
               const float* __restrict__ bias, u16* __restrict__ outb,
               float* __restrict__ outf)
{
  const int lane = threadIdx.x & 63;
  const int wv = threadIdx.x >> 6;
  const int l15 = lane & 15, g8 = lane >> 4;
  // XCD-aware swizzle: 1152 blocks, 8 XCDs, 144 contiguous per XCD.
  // XCD c handles rows 48c..48c+47 -> 3-row tap window stays in its 4MB L2.
  const int bid = blockIdx.x;
  const int sw = (bid & 7) * 144 + (bid >> 3);
  const int by = sw / 3, bx = sw % 3;
  const int y = by;
  const int x0 = bx * 128 + wv * 64;

  f32x4 acc[4][4];
  #pragma unroll
  for (int m = 0; m < 4; ++m)
    #pragma unroll
    for (int n = 0; n < 4; ++n)
      acc[m][n] = f32x4{0.f, 0.f, 0.f, 0.f};

  #pragma unroll
  for (int tap = 0; tap < 9; ++tap) {
    const int kr = tap / 3, kc = tap % 3;
    const u16* inr = in + (size_t)(y + kr) * ASTR + (size_t)(x0 + kc) * 64;
    #pragma unroll
    for (int ich = 0; ich < 2; ++ich) {
      const u16* wpi = wp + ((tap * 2 + ich) * 4) * 512 + lane * 8;  // coalesced A-frags
      bf16x8 a[4], b[4];
      #pragma unroll
      for (int m = 0; m < 4; ++m)
        a[m] = *(const bf16x8*)(wpi + m * 512);
      #pragma unroll
      for (int n = 0; n < 4; ++n)
        b[n] = *(const bf16x8*)(inr + (size_t)(n * 16 + l15) * 64 + ich * 32 + g8 * 8);
      #pragma unroll
      for (int m = 0; m < 4; ++m)
        #pragma unroll
        for (int n = 0; n < 4; ++n)
          acc[m][n] = __builtin_amdgcn_mfma_f32_16x16x32_bf16(a[m], b[n], acc[m][n], 0, 0, 0);
    }
  }

  const int oc_lo = g8 * 4;
  #pragma unroll
  for (int m = 0; m < 4; ++m) {
    const int oc0 = m * 16 + oc_lo;                  // D row = (lane>>4)*4 + reg
    const f32x4 bv = *(const f32x4*)(bias + oc0);
    #pragma unroll
    for (int n = 0; n < 4; ++n) {
      const int px = x0 + n * 16 + l15;              // D col = lane&15
      f32x4 v = acc[m][n] + bv;
      if constexpr (MODE == 0) {
        #pragma unroll
        for (int j = 0; j < 4; ++j) v[j] = v[j] > 0.f ? v[j] : 0.f;
      }
      if constexpr (MODE == 1) {
        const u16x4 r = *(const u16x4*)(outb + ((size_t)(y + 1) * AWP + (px + 1)) * 64 + oc0);
        #pragma unroll
        for (int j = 0; j < 4; ++j) v[j] += bf2f(r[j]);
      }
      if constexpr (MODE <= 1) {
        u16x4 s;
        #pragma unroll
        for (int j = 0; j < 4; ++j) s[j] = f2bf(v[j]);
        *(u16x4*)(outb + ((size_t)(y + 1) * AWP + (px + 1)) * 64 + oc0) = s;
      } else {
        // planar f32 store, only real channels
        #pragma unroll
        for (int j = 0; j < 4; ++j) {
          const int oc = oc0 + j;
          if (oc < 35) outf[(size_t)oc * NPIX + (size_t)y * WW + px] = v[j];
        }
      }
    }
  }
}

// ---------------- KPN apply: all 7 sections fused, shared gathers ----------------
__global__ __launch_bounds__(64)
void kpn_fused(const float* __restrict__ corep, const float* __restrict__ dpad,
               float* __restrict__ out)
{
  constexpr int OFFS[7] = {0, 2, 5, 9, 14, 20, 27};
  const int px = blockIdx.x * 64 + threadIdx.x;       // 2304*64 = NPIX exactly
  const int y = px / WW, x = px % WW;
  const float* base = dpad + (size_t)(y + 7) * DP + (x + 7);

  float ck[35];
  #pragma unroll
  for (int i = 0; i < 35; ++i) ck[i] = fabsf(corep[(size_t)i * NPIX + px]);

  float s[7], p[7][3];
  #pragma unroll
  for (int k = 0; k < 7; ++k) { s[k] = 0.f; p[k][0] = 0.f; p[k][1] = 0.f; p[k][2] = 0.f; }

  #pragma unroll
  for (int a = 0; a < 8; ++a) {
    #pragma unroll
    for (int b = 0; b < 8; ++b) {
      // section-independent mirror gather (each distinct cell counted once)
      float g[3];
      #pragma unroll
      for (int c = 0; c < 3; ++c) {
        const float* bc = base + c * DPLANE;
        float v = bc[a * DP + b];
        if (b > 0) v += bc[a * DP - b];
        if (a > 0) v += bc[-a * DP + b];
        if (a > 0 && b > 0) v += bc[-a * DP - b];
        g[c] = v;
      }
      const int d2 = a * a + b * b;
      int li = 0;                                     // integer floor sqrt, folds
      while ((li + 1) * (li + 1) <= d2) ++li;
      const bool exact = (li * li == d2);
      const int hraw = li + (exact ? 0 : 1);
      const float dd = sqrtf((float)d2);              // folds (d2 is constant)
      const float wlo = exact ? 1.f : ((float)hraw - dd);
      const float whi = exact ? 0.f : (dd - (float)li);
      const float mult = (float)(((a > 0) ? 2 : 1) * ((b > 0) ? 2 : 1));
      #pragma unroll
      for (int sec = 0; sec < 7; ++sec) {
        const int WIDE = sec + 2;
        if (a < WIDE && b < WIDE) {                   // compile-time prune
          const int lidx = li < WIDE - 1 ? li : WIDE - 1;
          const int hidx = hraw < WIDE - 1 ? hraw : WIDE - 1;
          const bool msk = d2 <= (WIDE - 1) * (WIDE - 1);
          float e;
          if (msk) e = __expf(wlo * ck[OFFS[sec] + lidx] + whi * ck[OFFS[sec] + hidx]);
          else e = 1.f;                               // masked: logit 0
          s[sec] += mult * e;
          p[sec][0] += e * g[0];
          p[sec][1] += e * g[1];
          p[sec][2] += e * g[2];
        }
      }
    }
  }
  #pragma unroll
  for (int sec = 0; sec < 7; ++sec) {
    const float inv = 1.f / s[sec];
    float* o = out + (size_t)(sec + 1) * NPIX3 + px;
    o[0] = p[sec][0] * inv;
    o[NPIX] = p[sec][1] * inv;
    o[2 * NPIX] = p[sec][2] * inv;
  }
}

// ---------------- launch ----------------
extern "C" void kernel_launch(void* const* d_in, const int* in_sizes, int n_in,
                              void* d_out, int out_size, void* d_ws, size_t ws_size,
                              hipStream_t stream)
{
  const float* d_est   = (const float*)d_in[0];
  const float* data    = (const float*)d_in[1];
  const float* w_first = (const float*)d_in[2];
  const float* b_first = (const float*)d_in[3];
  const float* w_blk1  = (const float*)d_in[4];
  const float* b_blk1  = (const float*)d_in[5];
  const float* w_blk2  = (const float*)d_in[6];
  const float* b_blk2  = (const float*)d_in[7];
  const float* w_out   = (const float*)d_in[8];
  const float* b_out   = (const float*)d_in[9];

  char* ws = (char*)d_ws;
  const size_t OFF_A1    = ACT_BYTES;
  const size_t OFF_CORE  = 2 * ACT_BYTES;
  const size_t OFF_DPAD  = OFF_CORE + (size_t)35 * NPIX * 4;
  const size_t OFF_WPACK = OFF_DPAD + (size_t)3 * DPLANE * 4;
  const size_t OFF_BPACK = OFF_WPACK + (size_t)7 * WSW * 2;
  const size_t OFF_WFR   = OFF_BPACK + 448 * 4;

  u16*   A0    = (u16*)(ws);
  u16*   A1    = (u16*)(ws + OFF_A1);
  float* corep = (float*)(ws + OFF_CORE);
  float* dpad  = (float*)(ws + OFF_DPAD);
  u16*   wpack = (u16*)(ws + OFF_WPACK);
  float* bpack = (float*)(ws + OFF_BPACK);
  float* wfr   = (float*)(ws + OFF_WFR);

  hipMemsetAsync(A0, 0, ACT_BYTES, stream);
  hipMemsetAsync(A1, 0, ACT_BYTES, stream);
  hipMemsetAsync(dpad, 0, (size_t)3 * DPLANE * 4, stream);
  // output 0 is an exact copy of `data`
  hipMemcpyAsync(d_out, data, (size_t)NPIX3 * 4, hipMemcpyDeviceToDevice, stream);

  repack_kern<<<1024, 256, 0, stream>>>(w_blk1, w_blk2, w_out, b_blk1, b_blk2, b_out,
                                        w_first, wpack, bpack, wfr);
  padcopy_kern<<<1728, 256, 0, stream>>>(data, dpad);
  conv1_kern<<<2304, dim3(64, 4), 0, stream>>>(d_est, wfr, b_first, A0);

  for (int i = 0; i < 3; ++i) {
    conv_mfma<0><<<1152, 128, 0, stream>>>(A0, wpack + (size_t)(2 * i) * WSW,
                                           bpack + (2 * i) * 64, A1, nullptr);
    conv_mfma<1><<<1152, 128, 0, stream>>>(A1, wpack + (size_t)(2 * i + 1) * WSW,
                                           bpack + (2 * i + 1) * 64, A0, nullptr);
  }
  conv_mfma<2><<<1152, 128, 0, stream>>>(A0, wpack + (size_t)6 * WSW,
                                         bpack + 6 * 64, nullptr, corep);

  kpn_fused<<<2304, 64, 0, stream>>>(corep, dpad, (float*)d_out);
}

// Round 7
// 410.870 us; speedup vs baseline: 1.6313x; 1.6313x over previous
//
#include <hip/hip_runtime.h>
#include <hip/hip_bf16.h>

typedef __attribute__((ext_vector_type(4))) float f32x4;
typedef __attribute__((ext_vector_type(8))) short bf16x8;
typedef __attribute__((ext_vector_type(4))) unsigned short u16x4;
typedef unsigned short u16;

constexpr int HH = 384, WW = 384;
constexpr int AWP = 386;               // padded activation width (+1 halo each side)
constexpr int ASTR = AWP * 64;         // elements per padded activation row
constexpr int NPIX = HH * WW;          // 147456
constexpr int NPIX3 = NPIX * 3;        // 442368 (one output tensor)
constexpr int DP = 398, DPLANE = DP * DP;  // data padded by 7 each side
constexpr size_t ACT_BYTES = (size_t)AWP * AWP * 64 * 2;  // 19,071,488
constexpr int WSW = 72 * 512;          // swizzled weights per conv: 72 iters * 64 lanes * 8

__device__ __forceinline__ u16 f2bf(float f) {
  union { __hip_bfloat16 h; u16 u; } v; v.h = __float2bfloat16(f); return v.u;
}
__device__ __forceinline__ float bf2f(u16 u) {
  union { float f; unsigned int i; } v; v.i = ((unsigned int)u) << 16; return v.f;
}

// ---------------- weight/bias repack ----------------
// wpack[c][iter][lane][j] bf16 pre-swizzled to MFMA A-fragment order:
//   iter = (tap*2 + ich)*4 + m;  oc = m*16 + (lane&15);  ic = ich*32 + (lane>>4)*8 + j
// bpack[c][oc] f32 (oc>=35 zeroed for conv 6); wfr[ictap][oc] f32 for first conv
__global__ void repack_kern(const float* __restrict__ w1, const float* __restrict__ w2,
                            const float* __restrict__ wo, const float* __restrict__ b1,
                            const float* __restrict__ b2, const float* __restrict__ bo,
                            const float* __restrict__ wf,
                            u16* __restrict__ wpack, float* __restrict__ bpack,
                            float* __restrict__ wfr)
{
  const int idx = blockIdx.x * 256 + threadIdx.x;
  constexpr int NW = 7 * WSW;
  if (idx < NW) {
    const int c = idx / WSW;
    const int r = idx % WSW;
    const int iter = r / 512;
    const int lane = (r % 512) / 8;
    const int j = r % 8;
    const int tap = iter >> 3;
    const int ich = (iter >> 2) & 1;
    const int m = iter & 3;
    const int oc = m * 16 + (lane & 15);
    const int ic = ich * 32 + (lane >> 4) * 8 + j;
    float v;
    if (c < 6) {
      const float* s = (c & 1) ? w2 : w1;
      v = s[(((c >> 1) * 64 + oc) * 64 + ic) * 9 + tap];
    } else {
      v = (oc < 35) ? wo[(oc * 64 + ic) * 9 + tap] : 0.f;
    }
    wpack[idx] = f2bf(v);
  } else if (idx < NW + 448) {
    const int t = idx - NW;
    const int c = t / 64, oc = t % 64;
    float v;
    if (c < 6) v = ((c & 1) ? b2 : b1)[(c >> 1) * 64 + oc];
    else v = (oc < 35) ? bo[oc] : 0.f;
    bpack[t] = v;
  } else if (idx < NW + 448 + 3456) {
    const int t = idx - NW - 448;
    const int ictap = t / 64, oc = t % 64;
    wfr[t] = wf[oc * 54 + ictap];
  }
}

// ---------------- pad-copy data (fp32, halo 7) ----------------
__global__ void padcopy_kern(const float* __restrict__ data, float* __restrict__ dpad)
{
  const int idx = blockIdx.x * 256 + threadIdx.x;  // exactly 442368 threads
  const int c = idx / NPIX, r = idx % NPIX;
  const int y = r / WW, x = r % WW;
  dpad[c * DPLANE + (y + 7) * DP + (x + 7)] = data[idx];
}

// ---------------- first conv: 6 -> 64, fp32 direct, writes NHWC bf16 ----------------
// block = (64 px, 4 oc-groups); each thread computes 16 oc for one pixel.
__global__ __launch_bounds__(256)
void conv1_kern(const float* __restrict__ din, const float* __restrict__ wr,
                const float* __restrict__ bias, u16* __restrict__ outb)
{
  const int px = blockIdx.x * 64 + threadIdx.x;   // 2304*64 = NPIX exactly
  const int ocg = threadIdx.y;                    // 0..3
  const int y = px / WW, x = px % WW;
  f32x4 acc[4];
  #pragma unroll
  for (int j = 0; j < 4; ++j) acc[j] = *(const f32x4*)(bias + ocg * 16 + j * 4);
  for (int ic = 0; ic < 6; ++ic) {
    #pragma unroll
    for (int kr = 0; kr < 3; ++kr) {
      const int yy = y + kr - 1;
      #pragma unroll
      for (int kc = 0; kc < 3; ++kc) {
        const int xx = x + kc - 1;
        float v = 0.f;
        if (yy >= 0 && yy < HH && xx >= 0 && xx < WW)
          v = din[ic * NPIX + yy * WW + xx];
        const float* w = wr + ((ic * 3 + kr) * 3 + kc) * 64 + ocg * 16;
        #pragma unroll
        for (int j = 0; j < 4; ++j) {
          const f32x4 wv = *(const f32x4*)(w + j * 4);
          acc[j] += wv * v;
        }
      }
    }
  }
  u16* ob = outb + ((size_t)(y + 1) * AWP + (x + 1)) * 64 + ocg * 16;
  #pragma unroll
  for (int j = 0; j < 4; ++j) {
    u16x4 s;
    #pragma unroll
    for (int t = 0; t < 4; ++t) s[t] = f2bf(acc[j][t]);
    *(u16x4*)(ob + j * 4) = s;
  }
}

// ---------------- MFMA implicit-GEMM 3x3 conv, 64->64 (or ->35 planar f32) ----------------
// MODE 0: +bias, relu, store bf16 NHWC padded
// MODE 1: +bias, +residual (in-place on outb), store bf16 NHWC padded
// MODE 2: +bias, store f32 planar [oc][pix] for oc < 35
template<int MODE>
__global__ __launch_bounds__(128)
void conv_mfma(const u16* __restrict__ in, const u16* __restrict__ wp,
               const float* __restrict__ bias, u16* __restrict__ outb,
               float* __restrict__ outf)
{
  const int lane = threadIdx.x & 63;
  const int wv = threadIdx.x >> 6;
  const int l15 = lane & 15, g8 = lane >> 4;
  // XCD-aware swizzle: 1152 blocks, 8 XCDs, 144 contiguous per XCD.
  // XCD c handles rows 48c..48c+47 -> 3-row tap window stays in its 4MB L2.
  const int bid = blockIdx.x;
  const int sw = (bid & 7) * 144 + (bid >> 3);
  const int by = sw / 3, bx = sw % 3;
  const int y = by;
  const int x0 = bx * 128 + wv * 64;

  f32x4 acc[4][4];
  #pragma unroll
  for (int m = 0; m < 4; ++m)
    #pragma unroll
    for (int n = 0; n < 4; ++n)
      acc[m][n] = f32x4{0.f, 0.f, 0.f, 0.f};

  #pragma unroll
  for (int tap = 0; tap < 9; ++tap) {
    const int kr = tap / 3, kc = tap % 3;
    const u16* inr = in + (size_t)(y + kr) * ASTR + (size_t)(x0 + kc) * 64;
    #pragma unroll
    for (int ich = 0; ich < 2; ++ich) {
      const u16* wpi = wp + ((tap * 2 + ich) * 4) * 512 + lane * 8;  // coalesced A-frags
      bf16x8 a[4], b[4];
      #pragma unroll
      for (int m = 0; m < 4; ++m)
        a[m] = *(const bf16x8*)(wpi + m * 512);
      #pragma unroll
      for (int n = 0; n < 4; ++n)
        b[n] = *(const bf16x8*)(inr + (size_t)(n * 16 + l15) * 64 + ich * 32 + g8 * 8);
      #pragma unroll
      for (int m = 0; m < 4; ++m)
        #pragma unroll
        for (int n = 0; n < 4; ++n)
          acc[m][n] = __builtin_amdgcn_mfma_f32_16x16x32_bf16(a[m], b[n], acc[m][n], 0, 0, 0);
    }
  }

  const int oc_lo = g8 * 4;
  #pragma unroll
  for (int m = 0; m < 4; ++m) {
    const int oc0 = m * 16 + oc_lo;                  // D row = (lane>>4)*4 + reg
    const f32x4 bv = *(const f32x4*)(bias + oc0);
    #pragma unroll
    for (int n = 0; n < 4; ++n) {
      const int px = x0 + n * 16 + l15;              // D col = lane&15
      f32x4 v = acc[m][n] + bv;
      if constexpr (MODE == 0) {
        #pragma unroll
        for (int j = 0; j < 4; ++j) v[j] = v[j] > 0.f ? v[j] : 0.f;
      }
      if constexpr (MODE == 1) {
        const u16x4 r = *(const u16x4*)(outb + ((size_t)(y + 1) * AWP + (px + 1)) * 64 + oc0);
        #pragma unroll
        for (int j = 0; j < 4; ++j) v[j] += bf2f(r[j]);
      }
      if constexpr (MODE <= 1) {
        u16x4 s;
        #pragma unroll
        for (int j = 0; j < 4; ++j) s[j] = f2bf(v[j]);
        *(u16x4*)(outb + ((size_t)(y + 1) * AWP + (px + 1)) * 64 + oc0) = s;
      } else {
        // planar f32 store, only real channels
        #pragma unroll
        for (int j = 0; j < 4; ++j) {
          const int oc = oc0 + j;
          if (oc < 35) outf[(size_t)oc * NPIX + (size_t)y * WW + px] = v[j];
        }
      }
    }
  }
}

// ---------------- KPN apply: 2-group partial fusion (shared gathers, bounded regs) ----------------
template<int SEC0, int NSEC>
__device__ __forceinline__ void kpn_grp_body(const float* __restrict__ corep,
                                             const float* __restrict__ dpad,
                                             float* __restrict__ out)
{
  constexpr int OFFS[7] = {0, 2, 5, 9, 14, 20, 27};
  constexpr int WMAX = SEC0 + NSEC + 1;          // widest WIDE in this group
  constexpr int CK0 = OFFS[SEC0];
  constexpr int CKN = OFFS[SEC0 + NSEC - 1] + (SEC0 + NSEC + 1) - CK0;

  const int px = blockIdx.x * 256 + threadIdx.x;      // 576*256 = NPIX exactly
  const int y = px / WW, x = px % WW;
  const float* base = dpad + (size_t)(y + 7) * DP + (x + 7);

  float ck[CKN];
  #pragma unroll
  for (int i = 0; i < CKN; ++i) ck[i] = fabsf(corep[(size_t)(CK0 + i) * NPIX + px]);

  float s[NSEC], p[NSEC][3];
  #pragma unroll
  for (int k = 0; k < NSEC; ++k) { s[k] = 0.f; p[k][0] = 0.f; p[k][1] = 0.f; p[k][2] = 0.f; }

  #pragma unroll
  for (int a = 0; a < WMAX; ++a) {
    #pragma unroll
    for (int b = 0; b < WMAX; ++b) {
      // section-independent mirror gather (each distinct cell loaded once)
      float g[3];
      #pragma unroll
      for (int c = 0; c < 3; ++c) {
        const float* bc = base + c * DPLANE;
        float v = bc[a * DP + b];
        if (b > 0) v += bc[a * DP - b];
        if (a > 0) v += bc[-a * DP + b];
        if (a > 0 && b > 0) v += bc[-a * DP - b];
        g[c] = v;
      }
      const int d2 = a * a + b * b;
      int li = 0;                                     // integer floor sqrt, folds
      while ((li + 1) * (li + 1) <= d2) ++li;
      const bool exact = (li * li == d2);
      const int hraw = li + (exact ? 0 : 1);
      const float dd = sqrtf((float)d2);              // folds (d2 is constant)
      const float wlo = exact ? 1.f : ((float)hraw - dd);
      const float whi = exact ? 0.f : (dd - (float)li);
      const float mult = (float)(((a > 0) ? 2 : 1) * ((b > 0) ? 2 : 1));
      #pragma unroll
      for (int t = 0; t < NSEC; ++t) {
        const int WIDE = SEC0 + t + 2;
        if (a < WIDE && b < WIDE) {                   // compile-time prune
          const int lidx = li < WIDE - 1 ? li : WIDE - 1;
          const int hidx = hraw < WIDE - 1 ? hraw : WIDE - 1;
          const bool msk = d2 <= (WIDE - 1) * (WIDE - 1);
          const int cb = OFFS[SEC0 + t] - CK0;
          float e;
          if (msk) e = __expf(wlo * ck[cb + lidx] + whi * ck[cb + hidx]);
          else e = 1.f;                               // masked: logit 0
          s[t] += mult * e;
          p[t][0] += e * g[0];
          p[t][1] += e * g[1];
          p[t][2] += e * g[2];
        }
      }
    }
  }
  #pragma unroll
  for (int t = 0; t < NSEC; ++t) {
    const float inv = 1.f / s[t];
    float* o = out + (size_t)(SEC0 + t + 1) * NPIX3 + px;
    o[0] = p[t][0] * inv;
    o[NPIX] = p[t][1] * inv;
    o[2 * NPIX] = p[t][2] * inv;
  }
}

__global__ __launch_bounds__(256, 4)
void kpn_split(const float* __restrict__ corep, const float* __restrict__ dpad,
               float* __restrict__ out)
{
  if (blockIdx.y == 0) kpn_grp_body<0, 5>(corep, dpad, out);   // WIDE 2-6
  else                 kpn_grp_body<5, 2>(corep, dpad, out);   // WIDE 7-8
}

// ---------------- launch ----------------
extern "C" void kernel_launch(void* const* d_in, const int* in_sizes, int n_in,
                              void* d_out, int out_size, void* d_ws, size_t ws_size,
                              hipStream_t stream)
{
  const float* d_est   = (const float*)d_in[0];
  const float* data    = (const float*)d_in[1];
  const float* w_first = (const float*)d_in[2];
  const float* b_first = (const float*)d_in[3];
  const float* w_blk1  = (const float*)d_in[4];
  const float* b_blk1  = (const float*)d_in[5];
  const float* w_blk2  = (const float*)d_in[6];
  const float* b_blk2  = (const float*)d_in[7];
  const float* w_out   = (const float*)d_in[8];
  const float* b_out   = (const float*)d_in[9];

  char* ws = (char*)d_ws;
  const size_t OFF_A1    = ACT_BYTES;
  const size_t OFF_CORE  = 2 * ACT_BYTES;
  const size_t OFF_DPAD  = OFF_CORE + (size_t)35 * NPIX * 4;
  const size_t OFF_WPACK = OFF_DPAD + (size_t)3 * DPLANE * 4;
  const size_t OFF_BPACK = OFF_WPACK + (size_t)7 * WSW * 2;
  const size_t OFF_WFR   = OFF_BPACK + 448 * 4;

  u16*   A0    = (u16*)(ws);
  u16*   A1    = (u16*)(ws + OFF_A1);
  float* corep = (float*)(ws + OFF_CORE);
  float* dpad  = (float*)(ws + OFF_DPAD);
  u16*   wpack = (u16*)(ws + OFF_WPACK);
  float* bpack = (float*)(ws + OFF_BPACK);
  float* wfr   = (float*)(ws + OFF_WFR);

  hipMemsetAsync(A0, 0, ACT_BYTES, stream);
  hipMemsetAsync(A1, 0, ACT_BYTES, stream);
  hipMemsetAsync(dpad, 0, (size_t)3 * DPLANE * 4, stream);
  // output 0 is an exact copy of `data`
  hipMemcpyAsync(d_out, data, (size_t)NPIX3 * 4, hipMemcpyDeviceToDevice, stream);

  repack_kern<<<1024, 256, 0, stream>>>(w_blk1, w_blk2, w_out, b_blk1, b_blk2, b_out,
                                        w_first, wpack, bpack, wfr);
  padcopy_kern<<<1728, 256, 0, stream>>>(data, dpad);
  conv1_kern<<<2304, dim3(64, 4), 0, stream>>>(d_est, wfr, b_first, A0);

  for (int i = 0; i < 3; ++i) {
    conv_mfma<0><<<1152, 128, 0, stream>>>(A0, wpack + (size_t)(2 * i) * WSW,
                                           bpack + (2 * i) * 64, A1, nullptr);
    conv_mfma<1><<<1152, 128, 0, stream>>>(A1, wpack + (size_t)(2 * i + 1) * WSW,
                                           bpack + (2 * i + 1) * 64, A0, nullptr);
  }
  conv_mfma<2><<<1152, 128, 0, stream>>>(A0, wpack + (size_t)6 * WSW,
                                         bpack + 6 * 64, nullptr, corep);

  kpn_split<<<dim3(576, 2), 256, 0, stream>>>(corep, dpad, (float*)d_out);
}

// Round 8
// 343.949 us; speedup vs baseline: 1.9487x; 1.1946x over previous
//
#include <hip/hip_runtime.h>
#include <hip/hip_bf16.h>
#include <utility>

typedef __attribute__((ext_vector_type(4))) float f32x4;
typedef __attribute__((ext_vector_type(8))) short bf16x8;
typedef __attribute__((ext_vector_type(4))) unsigned short u16x4;
typedef unsigned short u16;

constexpr int HH = 384, WW = 384;
constexpr int AWP = 386;               // padded activation width (+1 halo each side)
constexpr int ASTR = AWP * 64;         // elements per padded activation row
constexpr int NPIX = HH * WW;          // 147456
constexpr int NPIX3 = NPIX * 3;        // 442368 (one output tensor)
constexpr int DP = 398, DPLANE = DP * DP;  // data padded by 7 each side
constexpr size_t ACT_BYTES = (size_t)AWP * AWP * 64 * 2;  // 19,071,488
constexpr int WSW = 72 * 512;          // swizzled weights per conv: 72 iters * 64 lanes * 8

__device__ __forceinline__ u16 f2bf(float f) {
  union { __hip_bfloat16 h; u16 u; } v; v.h = __float2bfloat16(f); return v.u;
}
__device__ __forceinline__ float bf2f(u16 u) {
  union { float f; unsigned int i; } v; v.i = ((unsigned int)u) << 16; return v.f;
}

// ---------------- weight/bias repack ----------------
__global__ void repack_kern(const float* __restrict__ w1, const float* __restrict__ w2,
                            const float* __restrict__ wo, const float* __restrict__ b1,
                            const float* __restrict__ b2, const float* __restrict__ bo,
                            const float* __restrict__ wf,
                            u16* __restrict__ wpack, float* __restrict__ bpack,
                            float* __restrict__ wfr)
{
  const int idx = blockIdx.x * 256 + threadIdx.x;
  constexpr int NW = 7 * WSW;
  if (idx < NW) {
    const int c = idx / WSW;
    const int r = idx % WSW;
    const int iter = r / 512;
    const int lane = (r % 512) / 8;
    const int j = r % 8;
    const int tap = iter >> 3;
    const int ich = (iter >> 2) & 1;
    const int m = iter & 3;
    const int oc = m * 16 + (lane & 15);
    const int ic = ich * 32 + (lane >> 4) * 8 + j;
    float v;
    if (c < 6) {
      const float* s = (c & 1) ? w2 : w1;
      v = s[(((c >> 1) * 64 + oc) * 64 + ic) * 9 + tap];
    } else {
      v = (oc < 35) ? wo[(oc * 64 + ic) * 9 + tap] : 0.f;
    }
    wpack[idx] = f2bf(v);
  } else if (idx < NW + 448) {
    const int t = idx - NW;
    const int c = t / 64, oc = t % 64;
    float v;
    if (c < 6) v = ((c & 1) ? b2 : b1)[(c >> 1) * 64 + oc];
    else v = (oc < 35) ? bo[oc] : 0.f;
    bpack[t] = v;
  } else if (idx < NW + 448 + 3456) {
    const int t = idx - NW - 448;
    const int ictap = t / 64, oc = t % 64;
    wfr[t] = wf[oc * 54 + ictap];
  }
}

// ---------------- pad-copy data (fp32, halo 7) ----------------
__global__ void padcopy_kern(const float* __restrict__ data, float* __restrict__ dpad)
{
  const int idx = blockIdx.x * 256 + threadIdx.x;  // exactly 442368 threads
  const int c = idx / NPIX, r = idx % NPIX;
  const int y = r / WW, x = r % WW;
  dpad[c * DPLANE + (y + 7) * DP + (x + 7)] = data[idx];
}

// ---------------- first conv: 6 -> 64, fp32 direct, writes NHWC bf16 ----------------
__global__ __launch_bounds__(256)
void conv1_kern(const float* __restrict__ din, const float* __restrict__ wr,
                const float* __restrict__ bias, u16* __restrict__ outb)
{
  const int px = blockIdx.x * 64 + threadIdx.x;   // 2304*64 = NPIX exactly
  const int ocg = threadIdx.y;                    // 0..3
  const int y = px / WW, x = px % WW;
  f32x4 acc[4];
  #pragma unroll
  for (int j = 0; j < 4; ++j) acc[j] = *(const f32x4*)(bias + ocg * 16 + j * 4);
  for (int ic = 0; ic < 6; ++ic) {
    #pragma unroll
    for (int kr = 0; kr < 3; ++kr) {
      const int yy = y + kr - 1;
      #pragma unroll
      for (int kc = 0; kc < 3; ++kc) {
        const int xx = x + kc - 1;
        float v = 0.f;
        if (yy >= 0 && yy < HH && xx >= 0 && xx < WW)
          v = din[ic * NPIX + yy * WW + xx];
        const float* w = wr + ((ic * 3 + kr) * 3 + kc) * 64 + ocg * 16;
        #pragma unroll
        for (int j = 0; j < 4; ++j) {
          const f32x4 wv = *(const f32x4*)(w + j * 4);
          acc[j] += wv * v;
        }
      }
    }
  }
  u16* ob = outb + ((size_t)(y + 1) * AWP + (x + 1)) * 64 + ocg * 16;
  #pragma unroll
  for (int j = 0; j < 4; ++j) {
    u16x4 s;
    #pragma unroll
    for (int t = 0; t < 4; ++t) s[t] = f2bf(acc[j][t]);
    *(u16x4*)(ob + j * 4) = s;
  }
}

// ---------------- MFMA implicit-GEMM 3x3 conv, K-split across 2 waves ----------------
// block = 128 thr = 2 waves; wave wv handles ich=wv half of K; LDS combine.
// MODE 0: +bias, relu, store bf16 NHWC padded
// MODE 1: +bias, +residual (in-place on outb), store bf16 NHWC padded
// MODE 2: +bias, store f32 planar [oc][pix] for oc < 35
template<int MODE>
__global__ __launch_bounds__(128, 3)
void conv_mfma(const u16* __restrict__ in, const u16* __restrict__ wp,
               const float* __restrict__ bias, u16* __restrict__ outb,
               float* __restrict__ outf)
{
  __shared__ float red[64 * 64];                   // 16 KB: wave1's partial acc
  const int lane = threadIdx.x & 63;
  const int wv = threadIdx.x >> 6;                 // K-half: ich = wv
  const int l15 = lane & 15, g8 = lane >> 4;
  // XCD-aware swizzle: 2304 blocks = 8 XCDs * 288 (48 rows * 6 col-blocks each)
  const int bid = blockIdx.x;
  const int sw = (bid & 7) * 288 + (bid >> 3);
  const int y = sw / 6;
  const int x0 = (sw % 6) * 64;
  const int ich = wv;

  f32x4 acc[4][4];
  #pragma unroll
  for (int m = 0; m < 4; ++m)
    #pragma unroll
    for (int n = 0; n < 4; ++n)
      acc[m][n] = f32x4{0.f, 0.f, 0.f, 0.f};

  #pragma unroll
  for (int tap = 0; tap < 9; ++tap) {
    const int kr = tap / 3, kc = tap % 3;
    const u16* inr = in + (size_t)(y + kr) * ASTR + (size_t)(x0 + kc) * 64;
    const u16* wpi = wp + ((tap * 2 + ich) * 4) * 512 + lane * 8;  // coalesced A-frags
    bf16x8 a[4], b[4];
    #pragma unroll
    for (int m = 0; m < 4; ++m)
      a[m] = *(const bf16x8*)(wpi + m * 512);
    #pragma unroll
    for (int n = 0; n < 4; ++n)
      b[n] = *(const bf16x8*)(inr + (size_t)(n * 16 + l15) * 64 + ich * 32 + g8 * 8);
    #pragma unroll
    for (int m = 0; m < 4; ++m)
      #pragma unroll
      for (int n = 0; n < 4; ++n)
        acc[m][n] = __builtin_amdgcn_mfma_f32_16x16x32_bf16(a[m], b[n], acc[m][n], 0, 0, 0);
  }

  if (wv == 1) {
    #pragma unroll
    for (int m = 0; m < 4; ++m)
      #pragma unroll
      for (int n = 0; n < 4; ++n)
        *(f32x4*)(red + (m * 4 + n) * 256 + lane * 4) = acc[m][n];
  }
  __syncthreads();
  if (wv == 1) return;

  const int oc_lo = g8 * 4;
  #pragma unroll
  for (int m = 0; m < 4; ++m) {
    const int oc0 = m * 16 + oc_lo;                  // D row = (lane>>4)*4 + reg
    const f32x4 bv = *(const f32x4*)(bias + oc0);
    #pragma unroll
    for (int n = 0; n < 4; ++n) {
      const int px = x0 + n * 16 + l15;              // D col = lane&15
      f32x4 v = acc[m][n] + *(const f32x4*)(red + (m * 4 + n) * 256 + lane * 4) + bv;
      if constexpr (MODE == 0) {
        #pragma unroll
        for (int j = 0; j < 4; ++j) v[j] = v[j] > 0.f ? v[j] : 0.f;
      }
      if constexpr (MODE == 1) {
        const u16x4 r = *(const u16x4*)(outb + ((size_t)(y + 1) * AWP + (px + 1)) * 64 + oc0);
        #pragma unroll
        for (int j = 0; j < 4; ++j) v[j] += bf2f(r[j]);
      }
      if constexpr (MODE <= 1) {
        u16x4 s;
        #pragma unroll
        for (int j = 0; j < 4; ++j) s[j] = f2bf(v[j]);
        *(u16x4*)(outb + ((size_t)(y + 1) * AWP + (px + 1)) * 64 + oc0) = s;
      } else {
        #pragma unroll
        for (int j = 0; j < 4; ++j) {
          const int oc = oc0 + j;
          if (oc < 35) outf[(size_t)oc * NPIX + (size_t)y * WW + px] = v[j];
        }
      }
    }
  }
}

// ---------------- KPN apply: template-fold sweep (guaranteed static indexing) ----------------
constexpr int isqrt_(int d2) { int li = 0; while ((li + 1) * (li + 1) <= d2) ++li; return li; }
constexpr double csqrt_(double x) {
  double g = x < 1.0 ? 1.0 : x;
  for (int i = 0; i < 60; ++i) g = 0.5 * (g + x / g);
  return g;
}
constexpr int KOFFS[7] = {0, 2, 5, 9, 14, 20, 27};

template<int SEC0, int NSEC, int CKN, int A, int B, int T>
__device__ __forceinline__ void kpn_sec_one(const float (&g)[3], const float (&ck)[CKN],
                                            float (&s)[NSEC], float (&p)[NSEC][3])
{
  constexpr int WIDE = SEC0 + T + 2;
  if constexpr (A < WIDE && B < WIDE) {
    constexpr int d2 = A * A + B * B;
    constexpr int li = isqrt_(d2);
    constexpr bool exact = (li * li == d2);
    constexpr int hraw = exact ? li : li + 1;
    constexpr float dd = (float)csqrt_((double)d2);
    constexpr float wlo = exact ? 1.0f : ((float)hraw - dd);
    constexpr float whi = exact ? 0.0f : (dd - (float)li);
    constexpr float mult = ((A > 0) ? 2.0f : 1.0f) * ((B > 0) ? 2.0f : 1.0f);
    constexpr int lidx = li < WIDE - 1 ? li : WIDE - 1;
    constexpr int hidx = hraw < WIDE - 1 ? hraw : WIDE - 1;
    constexpr bool msk = d2 <= (WIDE - 1) * (WIDE - 1);
    constexpr int cb = KOFFS[SEC0 + T] - KOFFS[SEC0];
    float e;
    if constexpr (msk) e = __expf(wlo * ck[cb + lidx] + whi * ck[cb + hidx]);
    else e = 1.0f;                                   // masked: logit 0, still in softmax
    s[T] += mult * e;
    p[T][0] += e * g[0];
    p[T][1] += e * g[1];
    p[T][2] += e * g[2];
  }
}

template<int SEC0, int NSEC, int CKN, int A, int B, int... Ts>
__device__ __forceinline__ void kpn_secs(std::integer_sequence<int, Ts...>,
                                         const float (&g)[3], const float (&ck)[CKN],
                                         float (&s)[NSEC], float (&p)[NSEC][3])
{
  (kpn_sec_one<SEC0, NSEC, CKN, A, B, Ts>(g, ck, s, p), ...);
}

template<int SEC0, int NSEC, int CKN, int WMAX, int C>
__device__ __forceinline__ void kpn_cell(const float* __restrict__ base,
                                         const float (&ck)[CKN],
                                         float (&s)[NSEC], float (&p)[NSEC][3])
{
  constexpr int A = C / WMAX, B = C % WMAX;
  float g[3];
  #pragma unroll
  for (int c = 0; c < 3; ++c) {
    const float* bc = base + c * DPLANE;
    float v = bc[A * DP + B];
    if constexpr (B > 0) v += bc[A * DP - B];
    if constexpr (A > 0) v += bc[-A * DP + B];
    if constexpr (A > 0 && B > 0) v += bc[-A * DP - B];
    g[c] = v;
  }
  kpn_secs<SEC0, NSEC, CKN, A, B>(std::make_integer_sequence<int, NSEC>{}, g, ck, s, p);
}

template<int SEC0, int NSEC, int CKN, int WMAX, int... Cs>
__device__ __forceinline__ void kpn_cells(std::integer_sequence<int, Cs...>,
                                          const float* __restrict__ base,
                                          const float (&ck)[CKN],
                                          float (&s)[NSEC], float (&p)[NSEC][3])
{
  (kpn_cell<SEC0, NSEC, CKN, WMAX, Cs>(base, ck, s, p), ...);
}

template<int SEC0, int NSEC>
__device__ __forceinline__ void kpn_grp_body(const float* __restrict__ corep,
                                             const float* __restrict__ dpad,
                                             float* __restrict__ out)
{
  constexpr int WMAX = SEC0 + NSEC + 1;          // widest WIDE in this group
  constexpr int CK0 = KOFFS[SEC0];
  constexpr int CKN = KOFFS[SEC0 + NSEC - 1] + (SEC0 + NSEC + 1) - CK0;

  const int px = blockIdx.x * 256 + threadIdx.x;      // 576*256 = NPIX exactly
  const int y = px / WW, x = px % WW;
  const float* base = dpad + (size_t)(y + 7) * DP + (x + 7);

  float ck[CKN];
  #pragma unroll
  for (int i = 0; i < CKN; ++i) ck[i] = fabsf(corep[(size_t)(CK0 + i) * NPIX + px]);

  float s[NSEC], p[NSEC][3];
  #pragma unroll
  for (int k = 0; k < NSEC; ++k) { s[k] = 0.f; p[k][0] = 0.f; p[k][1] = 0.f; p[k][2] = 0.f; }

  kpn_cells<SEC0, NSEC, CKN, WMAX>(std::make_integer_sequence<int, WMAX * WMAX>{},
                                   base, ck, s, p);

  #pragma unroll
  for (int t = 0; t < NSEC; ++t) {
    const float inv = 1.f / s[t];
    float* o = out + (size_t)(SEC0 + t + 1) * NPIX3 + px;
    o[0] = p[t][0] * inv;
    o[NPIX] = p[t][1] * inv;
    o[2 * NPIX] = p[t][2] * inv;
  }
}

__global__ __launch_bounds__(256, 4)
void kpn_split(const float* __restrict__ corep, const float* __restrict__ dpad,
               float* __restrict__ out)
{
  if (blockIdx.y == 0) kpn_grp_body<0, 5>(corep, dpad, out);   // WIDE 2-6
  else                 kpn_grp_body<5, 2>(corep, dpad, out);   // WIDE 7-8
}

// ---------------- launch ----------------
extern "C" void kernel_launch(void* const* d_in, const int* in_sizes, int n_in,
                              void* d_out, int out_size, void* d_ws, size_t ws_size,
                              hipStream_t stream)
{
  const float* d_est   = (const float*)d_in[0];
  const float* data    = (const float*)d_in[1];
  const float* w_first = (const float*)d_in[2];
  const float* b_first = (const float*)d_in[3];
  const float* w_blk1  = (const float*)d_in[4];
  const float* b_blk1  = (const float*)d_in[5];
  const float* w_blk2  = (const float*)d_in[6];
  const float* b_blk2  = (const float*)d_in[7];
  const float* w_out   = (const float*)d_in[8];
  const float* b_out   = (const float*)d_in[9];

  char* ws = (char*)d_ws;
  const size_t OFF_A1    = ACT_BYTES;
  const size_t OFF_CORE  = 2 * ACT_BYTES;
  const size_t OFF_DPAD  = OFF_CORE + (size_t)35 * NPIX * 4;
  const size_t OFF_WPACK = OFF_DPAD + (size_t)3 * DPLANE * 4;
  const size_t OFF_BPACK = OFF_WPACK + (size_t)7 * WSW * 2;
  const size_t OFF_WFR   = OFF_BPACK + 448 * 4;

  u16*   A0    = (u16*)(ws);
  u16*   A1    = (u16*)(ws + OFF_A1);
  float* corep = (float*)(ws + OFF_CORE);
  float* dpad  = (float*)(ws + OFF_DPAD);
  u16*   wpack = (u16*)(ws + OFF_WPACK);
  float* bpack = (float*)(ws + OFF_BPACK);
  float* wfr   = (float*)(ws + OFF_WFR);

  hipMemsetAsync(A0, 0, ACT_BYTES, stream);
  hipMemsetAsync(A1, 0, ACT_BYTES, stream);
  hipMemsetAsync(dpad, 0, (size_t)3 * DPLANE * 4, stream);
  // output 0 is an exact copy of `data`
  hipMemcpyAsync(d_out, data, (size_t)NPIX3 * 4, hipMemcpyDeviceToDevice, stream);

  repack_kern<<<1024, 256, 0, stream>>>(w_blk1, w_blk2, w_out, b_blk1, b_blk2, b_out,
                                        w_first, wpack, bpack, wfr);
  padcopy_kern<<<1728, 256, 0, stream>>>(data, dpad);
  conv1_kern<<<2304, dim3(64, 4), 0, stream>>>(d_est, wfr, b_first, A0);

  for (int i = 0; i < 3; ++i) {
    conv_mfma<0><<<2304, 128, 0, stream>>>(A0, wpack + (size_t)(2 * i) * WSW,
                                           bpack + (2 * i) * 64, A1, nullptr);
    conv_mfma<1><<<2304, 128, 0, stream>>>(A1, wpack + (size_t)(2 * i + 1) * WSW,
                                           bpack + (2 * i + 1) * 64, A0, nullptr);
  }
  conv_mfma<2><<<2304, 128, 0, stream>>>(A0, wpack + (size_t)6 * WSW,
                                         bpack + 6 * 64, nullptr, corep);

  kpn_split<<<dim3(576, 2), 256, 0, stream>>>(corep, dpad, (float*)d_out);
}

// Round 9
// 294.374 us; speedup vs baseline: 2.2769x; 1.1684x over previous
//
#include <hip/hip_runtime.h>
#include <hip/hip_bf16.h>
#include <utility>

typedef __attribute__((ext_vector_type(4))) float f32x4;
typedef __attribute__((ext_vector_type(8))) short bf16x8;
typedef __attribute__((ext_vector_type(4))) unsigned short u16x4;
typedef unsigned short u16;

constexpr int HH = 384, WW = 384;
constexpr int AWP = 386;               // padded activation width (+1 halo each side)
constexpr int ASTR = AWP * 64;         // elements per padded activation row
constexpr int NPIX = HH * WW;          // 147456
constexpr int NPIX3 = NPIX * 3;        // 442368 (one output tensor)
constexpr int DP = 398, DPLANE = DP * DP;  // data padded by 7 each side
constexpr size_t ACT_BYTES = (size_t)AWP * AWP * 64 * 2;  // 19,071,488
constexpr int WSW = 72 * 512;          // swizzled weights per conv: 72 iters * 64 lanes * 8
constexpr int WP1N = 12 * 512;         // conv1 swizzled weights (K=96)

__device__ __forceinline__ u16 f2bf(float f) {
  union { __hip_bfloat16 h; u16 u; } v; v.h = __float2bfloat16(f); return v.u;
}
__device__ __forceinline__ float bf2f(u16 u) {
  union { float f; unsigned int i; } v; v.i = ((unsigned int)u) << 16; return v.f;
}

// ---------------- weight/bias repack ----------------
// wpack: 7 convs, A-frag order: iter=(tap*2+ich)*4+m; oc=m*16+(lane&15); ic=ich*32+(lane>>4)*8+j
// wp1: conv1 (6ic, K=96): iter=kb*4+m; oc=m*16+(lane&15); k=kb*32+(lane>>4)*8+j; tap=k/8, ic=k%8
__global__ void repack_kern(const float* __restrict__ w1, const float* __restrict__ w2,
                            const float* __restrict__ wo, const float* __restrict__ b1,
                            const float* __restrict__ b2, const float* __restrict__ bo,
                            const float* __restrict__ wf,
                            u16* __restrict__ wpack, float* __restrict__ bpack,
                            u16* __restrict__ wp1)
{
  const int idx = blockIdx.x * 256 + threadIdx.x;
  constexpr int NW = 7 * WSW;
  if (idx < NW) {
    const int c = idx / WSW;
    const int r = idx % WSW;
    const int iter = r / 512;
    const int lane = (r % 512) / 8;
    const int j = r % 8;
    const int tap = iter >> 3;
    const int ich = (iter >> 2) & 1;
    const int m = iter & 3;
    const int oc = m * 16 + (lane & 15);
    const int ic = ich * 32 + (lane >> 4) * 8 + j;
    float v;
    if (c < 6) {
      const float* s = (c & 1) ? w2 : w1;
      v = s[(((c >> 1) * 64 + oc) * 64 + ic) * 9 + tap];
    } else {
      v = (oc < 35) ? wo[(oc * 64 + ic) * 9 + tap] : 0.f;
    }
    wpack[idx] = f2bf(v);
  } else if (idx < NW + 448) {
    const int t = idx - NW;
    const int c = t / 64, oc = t % 64;
    float v;
    if (c < 6) v = ((c & 1) ? b2 : b1)[(c >> 1) * 64 + oc];
    else v = (oc < 35) ? bo[oc] : 0.f;
    bpack[t] = v;
  } else if (idx < NW + 448 + WP1N) {
    const int t = idx - NW - 448;
    const int iter = t / 512;
    const int lane = (t % 512) / 8;
    const int j = t % 8;
    const int m = iter & 3;
    const int kb = iter >> 2;
    const int oc = m * 16 + (lane & 15);
    const int k = kb * 32 + (lane >> 4) * 8 + j;
    const int tap = k >> 3, ic = k & 7;
    const float v = (tap < 9 && ic < 6) ? wf[oc * 54 + ic * 9 + tap] : 0.f;
    wp1[t] = f2bf(v);
  }
}

// ---------------- pad-copy data (fp32, halo 7) ----------------
__global__ void padcopy_kern(const float* __restrict__ data, float* __restrict__ dpad)
{
  const int idx = blockIdx.x * 256 + threadIdx.x;  // exactly 442368 threads
  const int c = idx / NPIX, r = idx % NPIX;
  const int y = r / WW, x = r % WW;
  dpad[c * DPLANE + (y + 7) * DP + (x + 7)] = data[idx];
}

// ---------------- pad data_with_est to NHWC8 bf16 (halo 1, ic 6->8 zero) ----------------
__global__ void pad6_kern(const float* __restrict__ din, u16* __restrict__ in8)
{
  const int px = blockIdx.x * 256 + threadIdx.x;   // 576*256 = NPIX exactly
  const int y = px / WW, x = px % WW;
  u16 vals[8];
  #pragma unroll
  for (int ic = 0; ic < 6; ++ic) vals[ic] = f2bf(din[ic * NPIX + px]);
  vals[6] = 0; vals[7] = 0;
  u16* o = in8 + ((size_t)(y + 1) * AWP + (x + 1)) * 8;
  *(u16x4*)(o) = u16x4{vals[0], vals[1], vals[2], vals[3]};
  *(u16x4*)(o + 4) = u16x4{vals[4], vals[5], vals[6], vals[7]};
}

// ---------------- conv1 via MFMA: 8ch NHWC bf16 -> 64, K=96 ----------------
__global__ __launch_bounds__(64)
void conv1_mfma(const u16* __restrict__ in8, const u16* __restrict__ wp,
                const float* __restrict__ bias, u16* __restrict__ outb)
{
  const int lane = threadIdx.x;
  const int l15 = lane & 15, g8 = lane >> 4;
  // XCD swizzle: 2304 = 8 * 288
  const int bid = blockIdx.x;
  const int sw = (bid & 7) * 288 + (bid >> 3);
  const int y = sw / 6;
  const int x0 = (sw % 6) * 64;

  f32x4 acc[4][4];
  #pragma unroll
  for (int m = 0; m < 4; ++m)
    #pragma unroll
    for (int n = 0; n < 4; ++n)
      acc[m][n] = f32x4{0.f, 0.f, 0.f, 0.f};

  #pragma unroll
  for (int kb = 0; kb < 3; ++kb) {
    const int tap = kb * 4 + g8;
    const int vt = tap < 9 ? tap : 0;                // dup tap0 for pad (weights are 0)
    const int kr = vt / 3, kc = vt % 3;
    const u16* inr = in8 + ((size_t)(y + kr) * AWP + x0 + kc) * 8;
    bf16x8 a[4], b[4];
    #pragma unroll
    for (int m = 0; m < 4; ++m)
      a[m] = *(const bf16x8*)(wp + (kb * 4 + m) * 512 + lane * 8);
    #pragma unroll
    for (int n = 0; n < 4; ++n)
      b[n] = *(const bf16x8*)(inr + (size_t)(n * 16 + l15) * 8);
    #pragma unroll
    for (int m = 0; m < 4; ++m)
      #pragma unroll
      for (int n = 0; n < 4; ++n)
        acc[m][n] = __builtin_amdgcn_mfma_f32_16x16x32_bf16(a[m], b[n], acc[m][n], 0, 0, 0);
  }

  const int oc_lo = g8 * 4;
  #pragma unroll
  for (int m = 0; m < 4; ++m) {
    const int oc0 = m * 16 + oc_lo;
    const f32x4 bv = *(const f32x4*)(bias + oc0);
    #pragma unroll
    for (int n = 0; n < 4; ++n) {
      const int px = x0 + n * 16 + l15;
      const f32x4 v = acc[m][n] + bv;
      u16x4 s;
      #pragma unroll
      for (int j = 0; j < 4; ++j) s[j] = f2bf(v[j]);
      *(u16x4*)(outb + ((size_t)(y + 1) * AWP + (px + 1)) * 64 + oc0) = s;
    }
  }
}

// ---------------- MFMA implicit-GEMM 3x3 conv, K-split across 2 waves ----------------
// MODE 0: +bias, relu; MODE 1: +bias,+residual; MODE 2: +bias, f32 planar (oc<35)
template<int MODE>
__global__ __launch_bounds__(128, 3)
void conv_mfma(const u16* __restrict__ in, const u16* __restrict__ wp,
               const float* __restrict__ bias, u16* __restrict__ outb,
               float* __restrict__ outf)
{
  __shared__ float red[64 * 64];                   // 16 KB: wave1's partial acc
  const int lane = threadIdx.x & 63;
  const int wv = threadIdx.x >> 6;                 // K-half: ich = wv
  const int l15 = lane & 15, g8 = lane >> 4;
  // XCD-aware swizzle: 2304 blocks = 8 XCDs * 288 (48 rows * 6 col-blocks each)
  const int bid = blockIdx.x;
  const int sw = (bid & 7) * 288 + (bid >> 3);
  const int y = sw / 6;
  const int x0 = (sw % 6) * 64;
  const int ich = wv;

  f32x4 acc[4][4];
  #pragma unroll
  for (int m = 0; m < 4; ++m)
    #pragma unroll
    for (int n = 0; n < 4; ++n)
      acc[m][n] = f32x4{0.f, 0.f, 0.f, 0.f};

  #pragma unroll
  for (int tap = 0; tap < 9; ++tap) {
    const int kr = tap / 3, kc = tap % 3;
    const u16* inr = in + (size_t)(y + kr) * ASTR + (size_t)(x0 + kc) * 64;
    const u16* wpi = wp + ((tap * 2 + ich) * 4) * 512 + lane * 8;  // coalesced A-frags
    bf16x8 a[4], b[4];
    #pragma unroll
    for (int m = 0; m < 4; ++m)
      a[m] = *(const bf16x8*)(wpi + m * 512);
    #pragma unroll
    for (int n = 0; n < 4; ++n)
      b[n] = *(const bf16x8*)(inr + (size_t)(n * 16 + l15) * 64 + ich * 32 + g8 * 8);
    #pragma unroll
    for (int m = 0; m < 4; ++m)
      #pragma unroll
      for (int n = 0; n < 4; ++n)
        acc[m][n] = __builtin_amdgcn_mfma_f32_16x16x32_bf16(a[m], b[n], acc[m][n], 0, 0, 0);
  }

  if (wv == 1) {
    #pragma unroll
    for (int m = 0; m < 4; ++m)
      #pragma unroll
      for (int n = 0; n < 4; ++n)
        *(f32x4*)(red + (m * 4 + n) * 256 + lane * 4) = acc[m][n];
  }
  __syncthreads();
  if (wv == 1) return;

  const int oc_lo = g8 * 4;
  #pragma unroll
  for (int m = 0; m < 4; ++m) {
    const int oc0 = m * 16 + oc_lo;                  // D row = (lane>>4)*4 + reg
    const f32x4 bv = *(const f32x4*)(bias + oc0);
    #pragma unroll
    for (int n = 0; n < 4; ++n) {
      const int px = x0 + n * 16 + l15;              // D col = lane&15
      f32x4 v = acc[m][n] + *(const f32x4*)(red + (m * 4 + n) * 256 + lane * 4) + bv;
      if constexpr (MODE == 0) {
        #pragma unroll
        for (int j = 0; j < 4; ++j) v[j] = v[j] > 0.f ? v[j] : 0.f;
      }
      if constexpr (MODE == 1) {
        const u16x4 r = *(const u16x4*)(outb + ((size_t)(y + 1) * AWP + (px + 1)) * 64 + oc0);
        #pragma unroll
        for (int j = 0; j < 4; ++j) v[j] += bf2f(r[j]);
      }
      if constexpr (MODE <= 1) {
        u16x4 s;
        #pragma unroll
        for (int j = 0; j < 4; ++j) s[j] = f2bf(v[j]);
        *(u16x4*)(outb + ((size_t)(y + 1) * AWP + (px + 1)) * 64 + oc0) = s;
      } else {
        #pragma unroll
        for (int j = 0; j < 4; ++j) {
          const int oc = oc0 + j;
          if (oc < 35) outf[(size_t)oc * NPIX + (size_t)y * WW + px] = v[j];
        }
      }
    }
  }
}

// ---------------- KPN apply: template-fold sweep (guaranteed static indexing) ----------------
constexpr int isqrt_(int d2) { int li = 0; while ((li + 1) * (li + 1) <= d2) ++li; return li; }
constexpr double csqrt_(double x) {
  double g = x < 1.0 ? 1.0 : x;
  for (int i = 0; i < 60; ++i) g = 0.5 * (g + x / g);
  return g;
}
constexpr int KOFFS[7] = {0, 2, 5, 9, 14, 20, 27};

template<int SEC0, int NSEC, int CKN, int A, int B, int T>
__device__ __forceinline__ void kpn_sec_one(const float (&g)[3], const float (&ck)[CKN],
                                            float (&s)[NSEC], float (&p)[NSEC][3])
{
  constexpr int WIDE = SEC0 + T + 2;
  if constexpr (A < WIDE && B < WIDE) {
    constexpr int d2 = A * A + B * B;
    constexpr int li = isqrt_(d2);
    constexpr bool exact = (li * li == d2);
    constexpr int hraw = exact ? li : li + 1;
    constexpr float dd = (float)csqrt_((double)d2);
    constexpr float wlo = exact ? 1.0f : ((float)hraw - dd);
    constexpr float whi = exact ? 0.0f : (dd - (float)li);
    constexpr float mult = ((A > 0) ? 2.0f : 1.0f) * ((B > 0) ? 2.0f : 1.0f);
    constexpr int lidx = li < WIDE - 1 ? li : WIDE - 1;
    constexpr int hidx = hraw < WIDE - 1 ? hraw : WIDE - 1;
    constexpr bool msk = d2 <= (WIDE - 1) * (WIDE - 1);
    constexpr int cb = KOFFS[SEC0 + T] - KOFFS[SEC0];
    float e;
    if constexpr (msk) e = __expf(wlo * ck[cb + lidx] + whi * ck[cb + hidx]);
    else e = 1.0f;                                   // masked: logit 0, still in softmax
    s[T] += mult * e;
    p[T][0] += e * g[0];
    p[T][1] += e * g[1];
    p[T][2] += e * g[2];
  }
}

template<int SEC0, int NSEC, int CKN, int A, int B, int... Ts>
__device__ __forceinline__ void kpn_secs(std::integer_sequence<int, Ts...>,
                                         const float (&g)[3], const float (&ck)[CKN],
                                         float (&s)[NSEC], float (&p)[NSEC][3])
{
  (kpn_sec_one<SEC0, NSEC, CKN, A, B, Ts>(g, ck, s, p), ...);
}

template<int SEC0, int NSEC, int CKN, int WMAX, int C>
__device__ __forceinline__ void kpn_cell(const float* __restrict__ base,
                                         const float (&ck)[CKN],
                                         float (&s)[NSEC], float (&p)[NSEC][3])
{
  constexpr int A = C / WMAX, B = C % WMAX;
  float g[3];
  #pragma unroll
  for (int c = 0; c < 3; ++c) {
    const float* bc = base + c * DPLANE;
    float v = bc[A * DP + B];
    if constexpr (B > 0) v += bc[A * DP - B];
    if constexpr (A > 0) v += bc[-A * DP + B];
    if constexpr (A > 0 && B > 0) v += bc[-A * DP - B];
    g[c] = v;
  }
  kpn_secs<SEC0, NSEC, CKN, A, B>(std::make_integer_sequence<int, NSEC>{}, g, ck, s, p);
}

template<int SEC0, int NSEC, int CKN, int WMAX, int... Cs>
__device__ __forceinline__ void kpn_cells(std::integer_sequence<int, Cs...>,
                                          const float* __restrict__ base,
                                          const float (&ck)[CKN],
                                          float (&s)[NSEC], float (&p)[NSEC][3])
{
  (kpn_cell<SEC0, NSEC, CKN, WMAX, Cs>(base, ck, s, p), ...);
}

template<int SEC0, int NSEC>
__device__ __forceinline__ void kpn_grp_body(const float* __restrict__ corep,
                                             const float* __restrict__ dpad,
                                             float* __restrict__ out)
{
  constexpr int WMAX = SEC0 + NSEC + 1;          // widest WIDE in this group
  constexpr int CK0 = KOFFS[SEC0];
  constexpr int CKN = KOFFS[SEC0 + NSEC - 1] + (SEC0 + NSEC + 1) - CK0;

  const int px = blockIdx.x * 256 + threadIdx.x;      // 576*256 = NPIX exactly
  const int y = px / WW, x = px % WW;
  const float* base = dpad + (size_t)(y + 7) * DP + (x + 7);

  float ck[CKN];
  #pragma unroll
  for (int i = 0; i < CKN; ++i) ck[i] = fabsf(corep[(size_t)(CK0 + i) * NPIX + px]);

  float s[NSEC], p[NSEC][3];
  #pragma unroll
  for (int k = 0; k < NSEC; ++k) { s[k] = 0.f; p[k][0] = 0.f; p[k][1] = 0.f; p[k][2] = 0.f; }

  kpn_cells<SEC0, NSEC, CKN, WMAX>(std::make_integer_sequence<int, WMAX * WMAX>{},
                                   base, ck, s, p);

  #pragma unroll
  for (int t = 0; t < NSEC; ++t) {
    const float inv = 1.f / s[t];
    float* o = out + (size_t)(SEC0 + t + 1) * NPIX3 + px;
    o[0] = p[t][0] * inv;
    o[NPIX] = p[t][1] * inv;
    o[2 * NPIX] = p[t][2] * inv;
  }
}

__global__ __launch_bounds__(256, 4)
void kpn_split(const float* __restrict__ corep, const float* __restrict__ dpad,
               float* __restrict__ out)
{
  if (blockIdx.y == 0) kpn_grp_body<0, 5>(corep, dpad, out);   // WIDE 2-6
  else                 kpn_grp_body<5, 2>(corep, dpad, out);   // WIDE 7-8
}

// ---------------- launch ----------------
extern "C" void kernel_launch(void* const* d_in, const int* in_sizes, int n_in,
                              void* d_out, int out_size, void* d_ws, size_t ws_size,
                              hipStream_t stream)
{
  const float* d_est   = (const float*)d_in[0];
  const float* data    = (const float*)d_in[1];
  const float* w_first = (const float*)d_in[2];
  const float* b_first = (const float*)d_in[3];
  const float* w_blk1  = (const float*)d_in[4];
  const float* b_blk1  = (const float*)d_in[5];
  const float* w_blk2  = (const float*)d_in[6];
  const float* b_blk2  = (const float*)d_in[7];
  const float* w_out   = (const float*)d_in[8];
  const float* b_out   = (const float*)d_in[9];

  char* ws = (char*)d_ws;
  const size_t OFF_A1    = ACT_BYTES;
  const size_t OFF_CORE  = 2 * ACT_BYTES;
  const size_t OFF_DPAD  = OFF_CORE + (size_t)35 * NPIX * 4;
  const size_t OFF_WPACK = OFF_DPAD + (size_t)3 * DPLANE * 4;
  const size_t OFF_BPACK = OFF_WPACK + (size_t)7 * WSW * 2;
  const size_t OFF_WP1   = OFF_BPACK + 448 * 4;
  const size_t OFF_IN8   = OFF_WP1 + (size_t)WP1N * 2;

  u16*   A0    = (u16*)(ws);
  u16*   A1    = (u16*)(ws + OFF_A1);
  float* corep = (float*)(ws + OFF_CORE);
  float* dpad  = (float*)(ws + OFF_DPAD);
  u16*   wpack = (u16*)(ws + OFF_WPACK);
  float* bpack = (float*)(ws + OFF_BPACK);
  u16*   wp1   = (u16*)(ws + OFF_WP1);
  u16*   in8   = (u16*)(ws + OFF_IN8);

  hipMemsetAsync(A0, 0, ACT_BYTES, stream);
  hipMemsetAsync(A1, 0, ACT_BYTES, stream);
  hipMemsetAsync(dpad, 0, (size_t)3 * DPLANE * 4, stream);
  hipMemsetAsync(in8, 0, (size_t)AWP * AWP * 8 * 2, stream);
  // output 0 is an exact copy of `data`
  hipMemcpyAsync(d_out, data, (size_t)NPIX3 * 4, hipMemcpyDeviceToDevice, stream);

  repack_kern<<<1034, 256, 0, stream>>>(w_blk1, w_blk2, w_out, b_blk1, b_blk2, b_out,
                                        w_first, wpack, bpack, wp1);
  padcopy_kern<<<1728, 256, 0, stream>>>(data, dpad);
  pad6_kern<<<576, 256, 0, stream>>>(d_est, in8);
  conv1_mfma<<<2304, 64, 0, stream>>>(in8, wp1, b_first, A0);

  for (int i = 0; i < 3; ++i) {
    conv_mfma<0><<<2304, 128, 0, stream>>>(A0, wpack + (size_t)(2 * i) * WSW,
                                           bpack + (2 * i) * 64, A1, nullptr);
    conv_mfma<1><<<2304, 128, 0, stream>>>(A1, wpack + (size_t)(2 * i + 1) * WSW,
                                           bpack + (2 * i + 1) * 64, A0, nullptr);
  }
  conv_mfma<2><<<2304, 128, 0, stream>>>(A0, wpack + (size_t)6 * WSW,
                                         bpack + 6 * 64, nullptr, corep);

  kpn_split<<<dim3(576, 2), 256, 0, stream>>>(corep, dpad, (float*)d_out);
}